// Round 9
// baseline (193.755 us; speedup 1.0000x reference)
//
#include <hip/hip_runtime.h>
#include <stdint.h>

#define BATCH 8192   // Gram K dimension
#define DIM   2048   // Gram M and N
#define NT    272    // symmetric tiles: 136 per Gram x 2 Grams
#define QTOT  (NT * 32)        // 8704 (tile, k-iter) work items
#define QPB   17               // 8704 / 512 blocks, exact
#define NSLOT 768              // total (block, tile) piece slots
#define DOTBLK (136 * 16)      // dot grid: 136 pairs x 16 chunks

typedef unsigned char  u8;
typedef unsigned short u16;
typedef unsigned int   u32;

using v8i   = __attribute__((ext_vector_type(8)))  int;
using v16f  = __attribute__((ext_vector_type(16))) float;

#if __has_builtin(__builtin_amdgcn_cvt_scalef32_pk_fp4_f32)
#define HW_FP4 1
#endif

// async global->LDS, 16B per lane; dest must be wave-uniform base + lane*16.
__device__ __forceinline__ void gl_lds16(const void* g, void* l) {
  __builtin_amdgcn_global_load_lds(
      (const __attribute__((address_space(1))) u32*)g,
      (__attribute__((address_space(3))) u32*)l, 16, 0, 0);
}

// Piece-slot compaction. Block b is a "straddler" (covers 2 tiles) iff
// (17*b mod 32) >= 16. Straddlers before b, closed form over the period-32
// residue pattern.
__device__ __forceinline__ int piece_base(int b) {
  const int m = b & 31;
  const int p = (m <= 16) ? (m >> 1) : (8 + ((m - 15) >> 1));
  return b + 16 * (b >> 5) + p;
}

// f32 -> bf16 (RNE), packed pair.
__device__ __forceinline__ u32 bfpair(float x, float y) {
  u32 bx = __float_as_uint(x);
  u32 by = __float_as_uint(y);
  bx = (bx + 0x7FFFu + ((bx >> 16) & 1u)) >> 16;
  by = (by + 0x7FFFu + ((by >> 16) & 1u)) >> 16;
  return bx | (by << 16);
}
__device__ __forceinline__ float bflo(u32 w) { return __uint_as_float(w << 16); }
__device__ __forceinline__ float bfhi(u32 w) { return __uint_as_float(w & 0xFFFF0000u); }

// Fallback f32 -> fp4 e2m1 nibble of (64*x), round-to-nearest.
__device__ __forceinline__ u32 nib4(float x) {
  float xs = x * 64.0f;
  float a  = fabsf(xs);
  u32 n = (u32)(a >= 0.25f) + (u32)(a >= 0.75f) + (u32)(a >= 1.25f) +
          (u32)(a >= 1.75f) + (u32)(a >= 2.5f)  + (u32)(a >= 3.5f)  +
          (u32)(a >= 5.0f);
  return n | (xs < 0.0f ? 8u : 0u);
}

// Pack 4 floats (quant domain = 64*x) into 4 e2m1 nibbles (u16).
__device__ __forceinline__ u16 pack4_fp4(float a, float b, float c, float d) {
#ifdef HW_FP4
  u32 w = __builtin_amdgcn_cvt_scalef32_pk_fp4_f32(0u,  a * 64.0f, b * 64.0f, 1.0f, 0);
  w     = __builtin_amdgcn_cvt_scalef32_pk_fp4_f32(w,   c * 64.0f, d * 64.0f, 1.0f, 1);
  return (u16)w;   // nibble-order differences are k-permutations -> cancel
#else
  return (u16)(nib4(a) | (nib4(b) << 4) | (nib4(c) << 8) | (nib4(d) << 12));
#endif
}

// ---------------------------------------------------------------------------
// Kernel 1: fused transpose + f32->fp4 — round-0 version (fastest measured,
// 49.7-51.4 us; the ~2.4-2.8 TB/s wall proved pattern-independent across six
// structural rewrites, so this stays). src [8192][2048] f32 -> dst
// [2048][8192-fp4].
// ---------------------------------------------------------------------------
__global__ __launch_bounds__(256) void tcvt_fp4(
    const float* __restrict__ L, const float* __restrict__ T,
    u8* __restrict__ X, u8* __restrict__ Y)
{
  __shared__ u16 ls[64 * 68];   // [d][64 u16 payload + 4 pad]

  const int tid = threadIdx.x;

  int id = blockIdx.x;
  const float* src;
  u8* dst;
  if (id < 1024) { src = L; dst = X; }
  else           { src = T; dst = Y; id -= 1024; }
  const int d0 = (id & 31) * 64;
  const int b0 = (id >> 5) * 256;

  const int s  = tid & 15;          // d-slot (d = 4s..4s+3)
  const int g  = tid >> 4;          // b row-group
  const int sw = s & 12;

  float4 f[4][4];
#pragma unroll
  for (int j = 0; j < 4; ++j)
#pragma unroll
    for (int r = 0; r < 4; ++r)
      f[j][r] = *(const float4*)(src + (size_t)(b0 + j * 64 + g * 4 + r) * DIM
                                 + d0 + s * 4);

#pragma unroll
  for (int j = 0; j < 4; ++j) {
    const int w = (j * 16 + g) ^ sw;   // u16 column 0..63
    const float* fp[4] = {(const float*)&f[j][0], (const float*)&f[j][1],
                          (const float*)&f[j][2], (const float*)&f[j][3]};
#pragma unroll
    for (int i = 0; i < 4; ++i)
      ls[(s * 4 + i) * 68 + w] = pack4_fp4(fp[0][i], fp[1][i], fp[2][i], fp[3][i]);
  }
  __syncthreads();

  // Phase B: row d = 64 u16 = 128 B fp4; gsw = (d>>4)&3.
#pragma unroll
  for (int j2 = 0; j2 < 2; ++j2) {
    const int d   = (tid >> 3) + j2 * 32;
    const int o8  = tid & 7;
    const int gsw = (d >> 4) & 3;
    const int g1  = (2 * o8)     ^ gsw;
    const int g2  = (2 * o8 + 1) ^ gsw;
    uint2 a = *(const uint2*)&ls[d * 68 + g1 * 4];
    uint2 b = *(const uint2*)&ls[d * 68 + g2 * 4];
    uint4 v = {a.x, a.y, b.x, b.y};
    *(uint4*)(dst + (size_t)(d0 + d) * (BATCH / 2) + (b0 >> 1) + o8 * 16) = v;
  }
}

// ---------------------------------------------------------------------------
// Kernel 2: Gram tiles, MX-fp4, symmetric lower-triangle, balanced
// persistent schedule (512 blocks x exactly 17 k-iters), private piece-slot
// flush (round-10), diagonal-tile J-skip (round-11).
// Round-17: piece flush narrowed to bf16 pairs (RNE). Partial-Gram entries
// are O(100) sums of 3072 fp4-product terms; bf16 keeps ~3 digits and the
// induced dot error is ~1e-7 relative — far below the accepted fp4 noise.
// Halves flush writes (50->25 MB) and dot reads.
// ---------------------------------------------------------------------------
__global__ __launch_bounds__(256, 2) void gram_fp4(
    const u8* __restrict__ X, const u8* __restrict__ Y,
    u32* __restrict__ P)
{
  __shared__ u8 ls[2][2][16384];   // [buf][panel I/J][128 rows x 128 B]

  const int tid = threadIdx.x;
  const int bid = blockIdx.x;

  const int wave = tid >> 6;
  const int lane = tid & 63;
  const int wr = (wave >> 1) * 64;
  const int wc = (wave & 1) * 64;
  const int lr = lane & 31;
  const int kh = lane >> 5;          // 16B chunk half within a 32B k-step

  // Staging geometry (block-constant): 16 KB/panel = 4 rounds x 256 x 16 B.
  u32 sdst[4]; int srow[4], sgc16[4];
#pragma unroll
  for (int rr = 0; rr < 4; ++rr) {
    const int li  = rr * 256 + tid;
    const int row = li >> 3;          // 8 chunks of 16B per 128B row
    const int p   = li & 7;
    sdst[rr]  = (u32)(row * 128 + p * 16);
    srow[rr]  = row;
    sgc16[rr] = (p ^ (row & 7)) * 16;
  }

  // Fragment LDS byte addresses: [half][ks 0..3], one b128 each.
  u32 fa[2][4], fb[2][4];
#pragma unroll
  for (int h = 0; h < 2; ++h) {
    const int ra = wr + h * 32 + lr;
    const int rb = wc + h * 32 + lr;
#pragma unroll
    for (int ks = 0; ks < 4; ++ks) {
      const int c = 2 * ks + kh;      // logical 16B chunk 0..7
      fa[h][ks] = (u32)(ra * 128 + (c ^ (ra & 7)) * 16);
      fb[h][ks] = (u32)(rb * 128 + (c ^ (rb & 7)) * 16);
    }
  }

  v16f acc[2][2] = {};
  const int sc = 0x7F7F7F7F;          // e8m0 = 127 -> scale 1.0

  const int q0  = bid * QPB;
  const int t0b = q0 >> 5;            // block's first tile
  const int sl0 = piece_base(bid);    // block's first piece slot
  int cur_t = -1, buf = 0;
  bool diag = false;
  const u8* src = X;
  u32 soi[4], soj[4];

  for (int it = 0; it < QPB; ++it) {
    const int q = q0 + it;
    const int t = q >> 5;
    const int k = q & 31;

    if (t != cur_t) {                 // tile switch (uniform across block)
      // (a) set up + issue async staging of the NEW tile first
      const int ltile = (t < 136) ? t : t - 136;
      src = (t < 136) ? X : Y;
      int ti = 0;
      while ((ti + 1) * (ti + 2) / 2 <= ltile) ++ti;   // lower-tri decode
      const int tj = ltile - ti * (ti + 1) / 2;
      const int i0 = ti * 128;
      const int j0 = tj * 128;
      diag = (ti == tj);
#pragma unroll
      for (int rr = 0; rr < 4; ++rr) {
        soi[rr] = (u32)(i0 + srow[rr]) * (BATCH / 2) + sgc16[rr];
        soj[rr] = (u32)(j0 + srow[rr]) * (BATCH / 2) + sgc16[rr];
      }
      const u32 kb = (u32)k * 128;    // 128 B fp4 = 256 k per iter
#pragma unroll
      for (int rr = 0; rr < 4; ++rr)
        gl_lds16(src + soi[rr] + kb, &ls[buf][0][sdst[rr]]);
      if (!diag)
#pragma unroll
        for (int rr = 0; rr < 4; ++rr)
          gl_lds16(src + soj[rr] + kb, &ls[buf][1][sdst[rr]]);
      // (b) flush previous tile's accumulator: bf16-pair stores into the
      //     private piece slot (hides under the staging just issued).
      if (cur_t >= 0) {
        uint2* o = (uint2*)(P + (size_t)(sl0 + (cur_t - t0b)) * 8192);
#pragma unroll
        for (int h = 0; h < 2; ++h)
#pragma unroll
          for (int hc = 0; hc < 2; ++hc)
#pragma unroll
            for (int r4 = 0; r4 < 4; ++r4) {
              uint2 v = {bfpair(acc[h][hc][r4 * 4 + 0], acc[h][hc][r4 * 4 + 1]),
                         bfpair(acc[h][hc][r4 * 4 + 2], acc[h][hc][r4 * 4 + 3])};
              o[((h * 2 + hc) * 4 + r4) * 256 + tid] = v;
            }
#pragma unroll
        for (int h = 0; h < 2; ++h)
#pragma unroll
          for (int hc = 0; hc < 2; ++hc)
#pragma unroll
            for (int c2 = 0; c2 < 16; ++c2)
              acc[h][hc][c2] = 0.0f;
      }
      cur_t = t;
    }

    __syncthreads();                  // staging of buf done; buf^1 free
    if (it + 1 < QPB && ((q + 1) >> 5) == t) {
      const u32 kb = (u32)(k + 1) * 128;
#pragma unroll
      for (int rr = 0; rr < 4; ++rr)
        gl_lds16(src + soi[rr] + kb, &ls[buf ^ 1][0][sdst[rr]]);
      if (!diag)
#pragma unroll
        for (int rr = 0; rr < 4; ++rr)
          gl_lds16(src + soj[rr] + kb, &ls[buf ^ 1][1][sdst[rr]]);
    }

    const u8* pI = ls[buf][0];
    const u8* pJ = diag ? ls[buf][0] : ls[buf][1];
#pragma unroll
    for (int ks = 0; ks < 4; ++ks) {
      v8i a[2], b[2];
#pragma unroll
      for (int h = 0; h < 2; ++h) {
        int4 pa = *(const int4*)&pI[fa[h][ks]];
        a[h] = (v8i){pa.x, pa.y, pa.z, pa.w, 0, 0, 0, 0};
        int4 pb = *(const int4*)&pJ[fb[h][ks]];
        b[h] = (v8i){pb.x, pb.y, pb.z, pb.w, 0, 0, 0, 0};
      }
#pragma unroll
      for (int h = 0; h < 2; ++h)
#pragma unroll
        for (int hc = 0; hc < 2; ++hc)
          acc[h][hc] = __builtin_amdgcn_mfma_scale_f32_32x32x64_f8f6f4(
              a[h], b[hc], acc[h][hc], /*cbsz=fp4*/ 4, /*blgp=fp4*/ 4,
              0, sc, 0, sc);
    }
    buf ^= 1;
  }

  // final flush (same lane-slot order: permutation cancels in the dot)
  {
    uint2* o = (uint2*)(P + (size_t)(sl0 + (cur_t - t0b)) * 8192);
#pragma unroll
    for (int h = 0; h < 2; ++h)
#pragma unroll
      for (int hc = 0; hc < 2; ++hc)
#pragma unroll
        for (int r4 = 0; r4 < 4; ++r4) {
          uint2 v = {bfpair(acc[h][hc][r4 * 4 + 0], acc[h][hc][r4 * 4 + 1]),
                     bfpair(acc[h][hc][r4 * 4 + 2], acc[h][hc][r4 * 4 + 3])};
          o[((h * 2 + hc) * 4 + r4) * 256 + tid] = v;
        }
  }
}

// ---------------------------------------------------------------------------
// Kernel 3: weighted dot, atomic-free (round-16), bf16 pieces (round-17).
// Pieces summed elementwise in f32 BEFORE the product (identical slot order
// across pieces -> permutation cancels). Each block writes one partial to
// pd[bid]; fin reduces.
// ---------------------------------------------------------------------------
__device__ __forceinline__ int collect_pieces(int t, int* s) {
  const int qlo = 32 * t, qhi = 32 * t + 31;
  const int b_lo = qlo / 17, b_hi = qhi / 17;
  int n = 0;
  for (int b = b_lo; b <= b_hi; ++b) {
    const int tfirst = (17 * b) >> 5;
    s[n++] = piece_base(b) + (t - tfirst);
  }
  return n;   // 2 or 3
}

__global__ __launch_bounds__(256) void dot_kernel(
    const uint2* __restrict__ P2, float* __restrict__ pd)
{
  __shared__ float red[4];
  const int tid  = threadIdx.x;
  const int lane = tid & 63;
  const int lt   = blockIdx.x >> 4;   // pair index 0..135
  const int ch   = blockIdx.x & 15;   // 256-element chunk within tile

  int ti = 0;
  while ((ti + 1) * (ti + 2) / 2 <= lt) ++ti;
  const int tj = lt - ti * (ti + 1) / 2;
  const float w = (ti == tj) ? 1.0f : 2.0f;

  int sx[3], sy[3];
  const int nx = collect_pieces(lt, sx);
  const int ny = collect_pieces(136 + lt, sy);

  const int e = ch * 256 + tid;       // uint2 index within the 4096/tile
  float a0, a1, a2, a3, b0, b1, b2, b3;
  {
    uint2 u = P2[(size_t)sx[0] * 4096 + e];
    a0 = bflo(u.x); a1 = bfhi(u.x); a2 = bflo(u.y); a3 = bfhi(u.y);
    u = P2[(size_t)sx[1] * 4096 + e];
    a0 += bflo(u.x); a1 += bfhi(u.x); a2 += bflo(u.y); a3 += bfhi(u.y);
    if (nx == 3) {
      u = P2[(size_t)sx[2] * 4096 + e];
      a0 += bflo(u.x); a1 += bfhi(u.x); a2 += bflo(u.y); a3 += bfhi(u.y);
    }
  }
  {
    uint2 u = P2[(size_t)sy[0] * 4096 + e];
    b0 = bflo(u.x); b1 = bfhi(u.x); b2 = bflo(u.y); b3 = bfhi(u.y);
    u = P2[(size_t)sy[1] * 4096 + e];
    b0 += bflo(u.x); b1 += bfhi(u.x); b2 += bflo(u.y); b3 += bfhi(u.y);
    if (ny == 3) {
      u = P2[(size_t)sy[2] * 4096 + e];
      b0 += bflo(u.x); b1 += bfhi(u.x); b2 += bflo(u.y); b3 += bfhi(u.y);
    }
  }
  float s = (a0 * b0 + a1 * b1 + a2 * b2 + a3 * b3) * w;

#pragma unroll
  for (int off = 32; off > 0; off >>= 1)
    s += __shfl_down(s, off);
  if (lane == 0) red[tid >> 6] = s;
  __syncthreads();
  if (tid == 0)
    pd[blockIdx.x] = red[0] + red[1] + red[2] + red[3];
}

// ---------------------------------------------------------------------------
// Kernel 4: finalize — 1 block reduces the 2176 partials (8.7 KB) and
// writes the loss. No atomics anywhere in the pipeline.
// ---------------------------------------------------------------------------
__global__ __launch_bounds__(256) void fin_kernel(
    const float* __restrict__ pd, float* __restrict__ out)
{
  __shared__ float red[4];
  const int tid  = threadIdx.x;
  const int lane = tid & 63;
  float s = 0.0f;
  for (int i = tid; i < DOTBLK; i += 256) s += pd[i];
#pragma unroll
  for (int off = 32; off > 0; off >>= 1)
    s += __shfl_down(s, off);
  if (lane == 0) red[tid >> 6] = s;
  __syncthreads();
  if (tid == 0) {
    float S = red[0] + red[1] + red[2] + red[3];
    // fidelity = S / (B^2 * 64^4) = S * 2^-50
    float fid = S * 0x1.0p-50f;
    fid = fminf(fmaxf(fid, 0.0f), 1.0f);
    *out = 0.1f * fabsf(fid - 0.95f);
  }
}

extern "C" void kernel_launch(void* const* d_in, const int* in_sizes, int n_in,
                              void* d_out, int out_size, void* d_ws, size_t ws_size,
                              hipStream_t stream) {
  const float* L = (const float*)d_in[0];
  const float* T = (const float*)d_in[1];
  float* out = (float*)d_out;

  const size_t NF4 = (size_t)BATCH * DIM / 2;    // 8,388,608 B per fp4 tensor
  u8*    X   = (u8*)d_ws;
  u8*    Y   = (u8*)d_ws + NF4;
  u32*   P   = (u32*)((char*)d_ws + 2 * NF4);    // 768 piece slots x 32 KB bf16
  float* pd  = (float*)(P + (size_t)NSLOT * 8192);  // 2176 per-block partials

  tcvt_fp4<<<2048, 256, 0, stream>>>(L, T, X, Y);
  gram_fp4<<<512, 256, 0, stream>>>(X, Y, P);
  dot_kernel<<<DOTBLK, 256, 0, stream>>>((const uint2*)P, pd);
  fin_kernel<<<1, 256, 0, stream>>>(pd, out);
}

// Round 10
// 187.987 us; speedup vs baseline: 1.0307x; 1.0307x over previous
//
#include <hip/hip_runtime.h>
#include <stdint.h>

#define BATCH 8192   // Gram K dimension
#define DIM   2048   // Gram M and N
#define NT    272    // symmetric tiles: 136 per Gram x 2 Grams
#define QTOT  (NT * 32)        // 8704 (tile, k-iter) work items
#define GQPB  8                // k-iters per gram block (no tile straddle)
#define GBLK  (QTOT / GQPB)    // 1088 gram blocks = 4 pieces per tile
#define DOTBLK (136 * 16)      // dot grid: 136 pairs x 16 chunks

typedef unsigned char  u8;
typedef unsigned short u16;
typedef unsigned int   u32;

using v8i   = __attribute__((ext_vector_type(8)))  int;
using v16f  = __attribute__((ext_vector_type(16))) float;

#if __has_builtin(__builtin_amdgcn_cvt_scalef32_pk_fp4_f32)
#define HW_FP4 1
#endif

// async global->LDS, 16B per lane; dest must be wave-uniform base + lane*16.
__device__ __forceinline__ void gl_lds16(const void* g, void* l) {
  __builtin_amdgcn_global_load_lds(
      (const __attribute__((address_space(1))) u32*)g,
      (__attribute__((address_space(3))) u32*)l, 16, 0, 0);
}

// f32 -> bf16 (RNE), packed pair.
__device__ __forceinline__ u32 bfpair(float x, float y) {
  u32 bx = __float_as_uint(x);
  u32 by = __float_as_uint(y);
  bx = (bx + 0x7FFFu + ((bx >> 16) & 1u)) >> 16;
  by = (by + 0x7FFFu + ((by >> 16) & 1u)) >> 16;
  return bx | (by << 16);
}
__device__ __forceinline__ float bflo(u32 w) { return __uint_as_float(w << 16); }
__device__ __forceinline__ float bfhi(u32 w) { return __uint_as_float(w & 0xFFFF0000u); }

// Fallback f32 -> fp4 e2m1 nibble of (64*x), round-to-nearest.
__device__ __forceinline__ u32 nib4(float x) {
  float xs = x * 64.0f;
  float a  = fabsf(xs);
  u32 n = (u32)(a >= 0.25f) + (u32)(a >= 0.75f) + (u32)(a >= 1.25f) +
          (u32)(a >= 1.75f) + (u32)(a >= 2.5f)  + (u32)(a >= 3.5f)  +
          (u32)(a >= 5.0f);
  return n | (xs < 0.0f ? 8u : 0u);
}

// Pack 4 floats (quant domain = 64*x) into 4 e2m1 nibbles (u16).
__device__ __forceinline__ u16 pack4_fp4(float a, float b, float c, float d) {
#ifdef HW_FP4
  u32 w = __builtin_amdgcn_cvt_scalef32_pk_fp4_f32(0u,  a * 64.0f, b * 64.0f, 1.0f, 0);
  w     = __builtin_amdgcn_cvt_scalef32_pk_fp4_f32(w,   c * 64.0f, d * 64.0f, 1.0f, 1);
  return (u16)w;   // nibble-order differences are k-permutations -> cancel
#else
  return (u16)(nib4(a) | (nib4(b) << 4) | (nib4(c) << 8) | (nib4(d) << 12));
#endif
}

// ---------------------------------------------------------------------------
// Kernel 1: fused transpose + f32->fp4 — round-0 version (fastest measured;
// the ~2.4-2.8 TB/s wall proved pattern-independent across six rewrites).
// src [8192][2048] f32 -> dst [2048][8192-fp4].
// ---------------------------------------------------------------------------
__global__ __launch_bounds__(256) void tcvt_fp4(
    const float* __restrict__ L, const float* __restrict__ T,
    u8* __restrict__ X, u8* __restrict__ Y)
{
  __shared__ u16 ls[64 * 68];   // [d][64 u16 payload + 4 pad]

  const int tid = threadIdx.x;

  int id = blockIdx.x;
  const float* src;
  u8* dst;
  if (id < 1024) { src = L; dst = X; }
  else           { src = T; dst = Y; id -= 1024; }
  const int d0 = (id & 31) * 64;
  const int b0 = (id >> 5) * 256;

  const int s  = tid & 15;          // d-slot (d = 4s..4s+3)
  const int g  = tid >> 4;          // b row-group
  const int sw = s & 12;

  float4 f[4][4];
#pragma unroll
  for (int j = 0; j < 4; ++j)
#pragma unroll
    for (int r = 0; r < 4; ++r)
      f[j][r] = *(const float4*)(src + (size_t)(b0 + j * 64 + g * 4 + r) * DIM
                                 + d0 + s * 4);

#pragma unroll
  for (int j = 0; j < 4; ++j) {
    const int w = (j * 16 + g) ^ sw;   // u16 column 0..63
    const float* fp[4] = {(const float*)&f[j][0], (const float*)&f[j][1],
                          (const float*)&f[j][2], (const float*)&f[j][3]};
#pragma unroll
    for (int i = 0; i < 4; ++i)
      ls[(s * 4 + i) * 68 + w] = pack4_fp4(fp[0][i], fp[1][i], fp[2][i], fp[3][i]);
  }
  __syncthreads();

  // Phase B: row d = 64 u16 = 128 B fp4; gsw = (d>>4)&3.
#pragma unroll
  for (int j2 = 0; j2 < 2; ++j2) {
    const int d   = (tid >> 3) + j2 * 32;
    const int o8  = tid & 7;
    const int gsw = (d >> 4) & 3;
    const int g1  = (2 * o8)     ^ gsw;
    const int g2  = (2 * o8 + 1) ^ gsw;
    uint2 a = *(const uint2*)&ls[d * 68 + g1 * 4];
    uint2 b = *(const uint2*)&ls[d * 68 + g2 * 4];
    uint4 v = {a.x, a.y, b.x, b.y};
    *(uint4*)(dst + (size_t)(d0 + d) * (BATCH / 2) + (b0 >> 1) + o8 * 16) = v;
  }
}

// ---------------------------------------------------------------------------
// Kernel 2 (round-18): Gram tiles, MX-fp4, symmetric lower-triangle.
// Re-partition: 1088 blocks x exactly 8 k-iters; 8*b mod 32 in {0,8,16,24}
// so NO block straddles a tile -> in-loop tile switch, piece_base compaction
// and mid-loop flush all deleted; tile t has exactly 4 pieces at slots
// 4t..4t+3. Single-buffered LDS (32 KB) + __launch_bounds__(256,4):
// 4 blocks/CU resident so the per-iter vmcnt(0)+barrier drain of one block
// overlaps MFMA of the others (gram was drain-bound: inputs are L2/L3-
// resident 16.8 MB, MFMA-busy ~7 us, yet ~30 us at 2 blocks/CU).
// Staging geometry / swizzle / fragment addresses / MFMA loop / bf16 flush
// copied verbatim from the proven kernel. Diagonal tiles skip panel J.
// ---------------------------------------------------------------------------
__global__ __launch_bounds__(256, 4) void gram_fp4(
    const u8* __restrict__ X, const u8* __restrict__ Y,
    u32* __restrict__ P)
{
  __shared__ u8 ls[2][16384];   // [panel I/J][128 rows x 128 B], single k-buf

  const int tid = threadIdx.x;
  const int bid = blockIdx.x;

  const int wave = tid >> 6;
  const int lane = tid & 63;
  const int wr = (wave >> 1) * 64;
  const int wc = (wave & 1) * 64;
  const int lr = lane & 31;
  const int kh = lane >> 5;          // 16B chunk half within a 32B k-step

  // Staging geometry (block-constant): 16 KB/panel = 4 rounds x 256 x 16 B.
  u32 sdst[4]; int srow[4], sgc16[4];
#pragma unroll
  for (int rr = 0; rr < 4; ++rr) {
    const int li  = rr * 256 + tid;
    const int row = li >> 3;          // 8 chunks of 16B per 128B row
    const int p   = li & 7;
    sdst[rr]  = (u32)(row * 128 + p * 16);
    srow[rr]  = row;
    sgc16[rr] = (p ^ (row & 7)) * 16;
  }

  // Fragment LDS byte addresses: [half][ks 0..3], one b128 each.
  u32 fa[2][4], fb[2][4];
#pragma unroll
  for (int h = 0; h < 2; ++h) {
    const int ra = wr + h * 32 + lr;
    const int rb = wc + h * 32 + lr;
#pragma unroll
    for (int ks = 0; ks < 4; ++ks) {
      const int c = 2 * ks + kh;      // logical 16B chunk 0..7
      fa[h][ks] = (u32)(ra * 128 + (c ^ (ra & 7)) * 16);
      fb[h][ks] = (u32)(rb * 128 + (c ^ (rb & 7)) * 16);
    }
  }

  // Tile decode (one tile per block, uniform).
  const int t  = bid >> 2;            // tile 0..271
  const int k0 = (bid & 3) * GQPB;    // this block's first k-iter
  const int ltile = (t < 136) ? t : t - 136;
  const u8* src = (t < 136) ? X : Y;
  int ti = 0;
  while ((ti + 1) * (ti + 2) / 2 <= ltile) ++ti;   // lower-tri decode
  const int tj = ltile - ti * (ti + 1) / 2;
  const int i0 = ti * 128;
  const int j0 = tj * 128;
  const bool diag = (ti == tj);

  u32 soi[4], soj[4];
#pragma unroll
  for (int rr = 0; rr < 4; ++rr) {
    soi[rr] = (u32)(i0 + srow[rr]) * (BATCH / 2) + sgc16[rr];
    soj[rr] = (u32)(j0 + srow[rr]) * (BATCH / 2) + sgc16[rr];
  }

  v16f acc[2][2] = {};
  const int sc = 0x7F7F7F7F;          // e8m0 = 127 -> scale 1.0

  // Prologue: stage k-iter k0.
  {
    const u32 kb = (u32)k0 * 128;     // 128 B fp4 = 256 k per iter
#pragma unroll
    for (int rr = 0; rr < 4; ++rr)
      gl_lds16(src + soi[rr] + kb, &ls[0][sdst[rr]]);
    if (!diag)
#pragma unroll
      for (int rr = 0; rr < 4; ++rr)
        gl_lds16(src + soj[rr] + kb, &ls[1][sdst[rr]]);
  }

  for (int it = 0; it < GQPB; ++it) {
    __syncthreads();                  // implicit vmcnt(0): stage landed
    const u8* pI = ls[0];
    const u8* pJ = diag ? ls[0] : ls[1];
#pragma unroll
    for (int ks = 0; ks < 4; ++ks) {
      v8i a[2], b[2];
#pragma unroll
      for (int h = 0; h < 2; ++h) {
        int4 pa = *(const int4*)&pI[fa[h][ks]];
        a[h] = (v8i){pa.x, pa.y, pa.z, pa.w, 0, 0, 0, 0};
        int4 pb = *(const int4*)&pJ[fb[h][ks]];
        b[h] = (v8i){pb.x, pb.y, pb.z, pb.w, 0, 0, 0, 0};
      }
#pragma unroll
      for (int h = 0; h < 2; ++h)
#pragma unroll
        for (int hc = 0; hc < 2; ++hc)
          acc[h][hc] = __builtin_amdgcn_mfma_scale_f32_32x32x64_f8f6f4(
              a[h], b[hc], acc[h][hc], /*cbsz=fp4*/ 4, /*blgp=fp4*/ 4,
              0, sc, 0, sc);
    }
    if (it + 1 < GQPB) {
      __syncthreads();                // all reads of ls done; safe to restage
      const u32 kb = (u32)(k0 + it + 1) * 128;
#pragma unroll
      for (int rr = 0; rr < 4; ++rr)
        gl_lds16(src + soi[rr] + kb, &ls[0][sdst[rr]]);
      if (!diag)
#pragma unroll
        for (int rr = 0; rr < 4; ++rr)
          gl_lds16(src + soj[rr] + kb, &ls[1][sdst[rr]]);
    }
  }

  // Flush: bf16-pair stores into private slot bid (lane-slot order identical
  // across all pieces of a tile -> permutation cancels in the dot).
  {
    uint2* o = (uint2*)(P + (size_t)bid * 8192);
#pragma unroll
    for (int h = 0; h < 2; ++h)
#pragma unroll
      for (int hc = 0; hc < 2; ++hc)
#pragma unroll
        for (int r4 = 0; r4 < 4; ++r4) {
          uint2 v = {bfpair(acc[h][hc][r4 * 4 + 0], acc[h][hc][r4 * 4 + 1]),
                     bfpair(acc[h][hc][r4 * 4 + 2], acc[h][hc][r4 * 4 + 3])};
          o[((h * 2 + hc) * 4 + r4) * 256 + tid] = v;
        }
  }
}

// ---------------------------------------------------------------------------
// Kernel 3: weighted dot, atomic-free, bf16 pieces. Tile t's 4 pieces live
// at slots 4t..4t+3 (uniform, no compaction math). Pieces summed in f32
// BEFORE the product. Each block writes one partial to pd[bid].
// ---------------------------------------------------------------------------
__global__ __launch_bounds__(256) void dot_kernel(
    const uint2* __restrict__ P2, float* __restrict__ pd)
{
  __shared__ float red[4];
  const int tid  = threadIdx.x;
  const int lane = tid & 63;
  const int lt   = blockIdx.x >> 4;   // pair index 0..135
  const int ch   = blockIdx.x & 15;   // 256-element chunk within tile

  int ti = 0;
  while ((ti + 1) * (ti + 2) / 2 <= lt) ++ti;
  const int tj = lt - ti * (ti + 1) / 2;
  const float w = (ti == tj) ? 1.0f : 2.0f;

  const int e   = ch * 256 + tid;     // uint2 index within the 4096/slot
  const size_t sxb = (size_t)(4 * lt) * 4096 + e;          // X-tile pieces
  const size_t syb = (size_t)(4 * (136 + lt)) * 4096 + e;  // Y-tile pieces

  float a0 = 0.f, a1 = 0.f, a2 = 0.f, a3 = 0.f;
  float b0 = 0.f, b1 = 0.f, b2 = 0.f, b3 = 0.f;
#pragma unroll
  for (int i = 0; i < 4; ++i) {
    uint2 u = P2[sxb + (size_t)i * 4096];
    a0 += bflo(u.x); a1 += bfhi(u.x); a2 += bflo(u.y); a3 += bfhi(u.y);
  }
#pragma unroll
  for (int i = 0; i < 4; ++i) {
    uint2 u = P2[syb + (size_t)i * 4096];
    b0 += bflo(u.x); b1 += bfhi(u.x); b2 += bflo(u.y); b3 += bfhi(u.y);
  }
  float s = (a0 * b0 + a1 * b1 + a2 * b2 + a3 * b3) * w;

#pragma unroll
  for (int off = 32; off > 0; off >>= 1)
    s += __shfl_down(s, off);
  if (lane == 0) red[tid >> 6] = s;
  __syncthreads();
  if (tid == 0)
    pd[blockIdx.x] = red[0] + red[1] + red[2] + red[3];
}

// ---------------------------------------------------------------------------
// Kernel 4: finalize — 1 block reduces the 2176 partials (8.7 KB) and
// writes the loss. No atomics anywhere in the pipeline.
// ---------------------------------------------------------------------------
__global__ __launch_bounds__(256) void fin_kernel(
    const float* __restrict__ pd, float* __restrict__ out)
{
  __shared__ float red[4];
  const int tid  = threadIdx.x;
  const int lane = tid & 63;
  float s = 0.0f;
  for (int i = tid; i < DOTBLK; i += 256) s += pd[i];
#pragma unroll
  for (int off = 32; off > 0; off >>= 1)
    s += __shfl_down(s, off);
  if (lane == 0) red[tid >> 6] = s;
  __syncthreads();
  if (tid == 0) {
    float S = red[0] + red[1] + red[2] + red[3];
    // fidelity = S / (B^2 * 64^4) = S * 2^-50
    float fid = S * 0x1.0p-50f;
    fid = fminf(fmaxf(fid, 0.0f), 1.0f);
    *out = 0.1f * fabsf(fid - 0.95f);
  }
}

extern "C" void kernel_launch(void* const* d_in, const int* in_sizes, int n_in,
                              void* d_out, int out_size, void* d_ws, size_t ws_size,
                              hipStream_t stream) {
  const float* L = (const float*)d_in[0];
  const float* T = (const float*)d_in[1];
  float* out = (float*)d_out;

  const size_t NF4 = (size_t)BATCH * DIM / 2;    // 8,388,608 B per fp4 tensor
  u8*    X   = (u8*)d_ws;
  u8*    Y   = (u8*)d_ws + NF4;
  u32*   P   = (u32*)((char*)d_ws + 2 * NF4);    // 1088 piece slots x 32 KB bf16
  float* pd  = (float*)(P + (size_t)GBLK * 8192);   // 2176 per-block partials

  tcvt_fp4<<<2048, 256, 0, stream>>>(L, T, X, Y);
  gram_fp4<<<GBLK, 256, 0, stream>>>(X, Y, P);
  dot_kernel<<<DOTBLK, 256, 0, stream>>>((const uint2*)P, pd);
  fin_kernel<<<1, 256, 0, stream>>>(pd, out);
}